// Round 1
// baseline (433.554 us; speedup 1.0000x reference)
//
#include <hip/hip_runtime.h>
#include <hip/hip_bf16.h>

// Problem constants
#define BATCH 96
#define CH    96
#define SEQ   96
#define NHEAD 8
#define DK    96
#define DMODEL 768   // NHEAD*DK
#define GRP   8
#define EPSV  1e-5f

typedef __bf16 bf16x8 __attribute__((ext_vector_type(8)));
typedef float  f32x4  __attribute__((ext_vector_type(4)));
typedef unsigned short u16;

__device__ __forceinline__ u16 f2bf(float f) {
    union { float f; unsigned int u; } c; c.f = f;
    unsigned int u = c.u + 0x7fffu + ((c.u >> 16) & 1u);   // RNE
    return (u16)(u >> 16);
}

// ---------------------------------------------------------------------------
// 1) GroupNorm: x (96,96,1,96) -> xn fp32 + xn bf16.  One block per (b,g).
//    group g = channels [12g,12g+12), 1152 elems. 128 threads x 9 elems.
// ---------------------------------------------------------------------------
__global__ __launch_bounds__(128) void gn_kernel(
        const float* __restrict__ x, const float* __restrict__ gamma,
        const float* __restrict__ beta, float* __restrict__ xn,
        u16* __restrict__ xn_bf) {
    int bg = blockIdx.x;
    int b = bg >> 3, g = bg & 7;
    const float* xp = x + b * 9216 + g * 1152;
    float vals[9];
    float s = 0.f, ss = 0.f;
    #pragma unroll
    for (int r = 0; r < 9; ++r) {
        float v = xp[threadIdx.x + 128 * r];
        vals[r] = v; s += v; ss += v * v;
    }
    #pragma unroll
    for (int off = 32; off > 0; off >>= 1) {
        s  += __shfl_down(s, off);
        ss += __shfl_down(ss, off);
    }
    __shared__ float red[4];
    if ((threadIdx.x & 63) == 0) {
        red[(threadIdx.x >> 6) * 2]     = s;
        red[(threadIdx.x >> 6) * 2 + 1] = ss;
    }
    __syncthreads();
    s = red[0] + red[2]; ss = red[1] + red[3];
    float mu   = s * (1.0f / 1152.0f);
    float var  = ss * (1.0f / 1152.0f) - mu * mu;
    float rsig = rsqrtf(var + EPSV);
    #pragma unroll
    for (int r = 0; r < 9; ++r) {
        int e = threadIdx.x + 128 * r;
        int c = g * 12 + e / 96;
        float v = (vals[r] - mu) * rsig * gamma[c] + beta[c];
        int idx = b * 9216 + g * 1152 + e;
        xn[idx]    = v;
        xn_bf[idx] = f2bf(v);
    }
}

// ---------------------------------------------------------------------------
// 2) Weight transpose + bf16 cast.
//    seg 0..2: W (96,768) -> WT (768,96);  seg 3: Wo (768,96) -> WoT (96,768)
// ---------------------------------------------------------------------------
__global__ __launch_bounds__(256) void wconv_kernel(
        const float* __restrict__ Wq, const float* __restrict__ Wk,
        const float* __restrict__ Wv, const float* __restrict__ Wo,
        u16* __restrict__ WqT, u16* __restrict__ WkT,
        u16* __restrict__ WvT, u16* __restrict__ WoT) {
    int seg = blockIdx.y;
    const float* src = seg == 0 ? Wq : seg == 1 ? Wk : seg == 2 ? Wv : Wo;
    u16* dst = seg == 0 ? WqT : seg == 1 ? WkT : seg == 2 ? WvT : WoT;
    int idx = blockIdx.x * 256 + threadIdx.x;          // 73728 total
    if (idx < 73728) {
        if (seg < 3) {
            int n = idx / 96, k2 = idx - n * 96;        // dst[n][k2]
            dst[idx] = f2bf(src[k2 * 768 + n]);
        } else {
            int n = idx / 768, k2 = idx - n * 768;      // dst[n][k2]
            dst[idx] = f2bf(src[k2 * 96 + n]);
        }
    }
}

// ---------------------------------------------------------------------------
// 3) QKV GEMM:  t(9216x96) @ W(96x768) + b  -> {q,k,v} bf16 (b,s,h*96+d)
//    grid (72, 6, 3), block 256 (4 waves, 2x2 of 64x64 wave tiles)
// ---------------------------------------------------------------------------
__global__ __launch_bounds__(256) void qkv_kernel(
        const u16* __restrict__ xn_bf,
        const u16* __restrict__ WqT, const u16* __restrict__ WkT,
        const u16* __restrict__ WvT,
        const float* __restrict__ bq, const float* __restrict__ bk,
        const float* __restrict__ bv,
        u16* __restrict__ q, u16* __restrict__ k, u16* __restrict__ v) {
    int z = blockIdx.z;
    const u16* WT = z == 0 ? WqT : z == 1 ? WkT : WvT;
    const float* bias = z == 0 ? bq : z == 1 ? bk : bv;
    u16* out = z == 0 ? q : z == 1 ? k : v;

    int wave = threadIdx.x >> 6, lane = threadIdx.x & 63;
    int ln = lane & 15, quad = lane >> 4;
    int m0 = blockIdx.x * 128 + (wave >> 1) * 64;
    int n0 = blockIdx.y * 128 + (wave & 1) * 64;

    f32x4 acc[4][4] = {};
    #pragma unroll
    for (int kt = 0; kt < 3; ++kt) {
        bf16x8 a[4], bb[4];
        #pragma unroll
        for (int mt = 0; mt < 4; ++mt)
            a[mt] = *(const bf16x8*)(xn_bf + (m0 + mt * 16 + ln) * 96 + kt * 32 + quad * 8);
        #pragma unroll
        for (int nt = 0; nt < 4; ++nt)
            bb[nt] = *(const bf16x8*)(WT + (n0 + nt * 16 + ln) * 96 + kt * 32 + quad * 8);
        #pragma unroll
        for (int mt = 0; mt < 4; ++mt)
            #pragma unroll
            for (int nt = 0; nt < 4; ++nt)
                acc[mt][nt] = __builtin_amdgcn_mfma_f32_16x16x32_bf16(
                    a[mt], bb[nt], acc[mt][nt], 0, 0, 0);
    }
    #pragma unroll
    for (int mt = 0; mt < 4; ++mt) {
        int row = m0 + mt * 16 + quad * 4;
        #pragma unroll
        for (int nt = 0; nt < 4; ++nt) {
            int col = n0 + nt * 16 + ln;
            float bcol = bias[col];
            #pragma unroll
            for (int r = 0; r < 4; ++r)
                out[(size_t)(row + r) * DMODEL + col] = f2bf(acc[mt][nt][r] + bcol);
        }
    }
}

// ---------------------------------------------------------------------------
// 4) Attention per (b,h): scores=QK^T/sqrt(96), causal softmax (registers),
//    P@V with P bf16 via LDS round-trip, V^T staged in LDS.
//    grid 768, block 384 (6 waves; wave w owns query rows [16w,16w+16))
// ---------------------------------------------------------------------------
__global__ __launch_bounds__(384) void attn_kernel(
        const u16* __restrict__ q, const u16* __restrict__ k,
        const u16* __restrict__ v, u16* __restrict__ attn_out) {
    int b = blockIdx.x >> 3, h = blockIdx.x & 7;
    __shared__ __align__(16) u16 vt[96][104];
    __shared__ __align__(16) u16 pP[96][104];
    const size_t base = (size_t)b * 96 * DMODEL + h * 96;

    // stage V^T: vt[d][s] = v[b,s,h,d]
    for (int idx = threadIdx.x; idx < 9216; idx += 384) {
        int s = idx / 96, d = idx - s * 96;
        vt[d][s] = v[base + (size_t)s * DMODEL + d];
    }

    int wave = threadIdx.x >> 6, lane = threadIdx.x & 63;
    int ln = lane & 15, quad = lane >> 4;

    // scores: rows [16w..16w+16), all 96 cols (6 n-tiles), K=96 (3 k-steps)
    f32x4 accs[6] = {};
    #pragma unroll
    for (int kt = 0; kt < 3; ++kt) {
        bf16x8 a = *(const bf16x8*)(q + base + (size_t)(wave * 16 + ln) * DMODEL + kt * 32 + quad * 8);
        #pragma unroll
        for (int nt = 0; nt < 6; ++nt) {
            bf16x8 bb = *(const bf16x8*)(k + base + (size_t)(nt * 16 + ln) * DMODEL + kt * 32 + quad * 8);
            accs[nt] = __builtin_amdgcn_mfma_f32_16x16x32_bf16(a, bb, accs[nt], 0, 0, 0);
        }
    }

    // causal softmax in registers; C layout: row=quad*4+r, col=nt*16+ln
    const float scale = 0.10206207261596577f;   // 1/sqrt(96)
    #pragma unroll
    for (int r = 0; r < 4; ++r) {
        int row = wave * 16 + quad * 4 + r;
        float vals[6], m = -1e30f;
        #pragma unroll
        for (int nt = 0; nt < 6; ++nt) {
            int col = nt * 16 + ln;
            float sv = accs[nt][r] * scale;
            vals[nt] = (col <= row) ? sv : -1e30f;
            m = fmaxf(m, vals[nt]);
        }
        #pragma unroll
        for (int off = 1; off < 16; off <<= 1) m = fmaxf(m, __shfl_xor(m, off));
        float p[6], sum = 0.f;
        #pragma unroll
        for (int nt = 0; nt < 6; ++nt) {
            p[nt] = (vals[nt] > -1e29f) ? __expf(vals[nt] - m) : 0.f;
            sum += p[nt];
        }
        #pragma unroll
        for (int off = 1; off < 16; off <<= 1) sum += __shfl_xor(sum, off);
        float rinv = 1.0f / sum;
        #pragma unroll
        for (int nt = 0; nt < 6; ++nt)
            pP[row][nt * 16 + ln] = f2bf(p[nt] * rinv);
    }
    __syncthreads();   // vt visibility (pP rows are same-wave)

    // P @ V : M=16 (wave rows), N=96, K=96
    f32x4 acco[6] = {};
    #pragma unroll
    for (int kt = 0; kt < 3; ++kt) {
        bf16x8 a = *(const bf16x8*)(&pP[wave * 16 + ln][kt * 32 + quad * 8]);
        #pragma unroll
        for (int nt = 0; nt < 6; ++nt) {
            bf16x8 bb = *(const bf16x8*)(&vt[nt * 16 + ln][kt * 32 + quad * 8]);
            acco[nt] = __builtin_amdgcn_mfma_f32_16x16x32_bf16(a, bb, acco[nt], 0, 0, 0);
        }
    }
    #pragma unroll
    for (int nt = 0; nt < 6; ++nt) {
        int d = nt * 16 + ln;
        #pragma unroll
        for (int r = 0; r < 4; ++r) {
            int row = wave * 16 + quad * 4 + r;
            attn_out[base + (size_t)row * DMODEL + d] = f2bf(acco[nt][r]);
        }
    }
}

// ---------------------------------------------------------------------------
// 5) Out projection: attn(9216x768) @ Wo(768x96) + bo -> proj fp32 (9216x96)
//    grid 144, block 256 (4 waves; wave = 16 rows x 96 cols)
// ---------------------------------------------------------------------------
__global__ __launch_bounds__(256) void oproj_kernel(
        const u16* __restrict__ attn, const u16* __restrict__ WoT,
        const float* __restrict__ bo, float* __restrict__ proj) {
    int wave = threadIdx.x >> 6, lane = threadIdx.x & 63;
    int ln = lane & 15, quad = lane >> 4;
    int m0 = (blockIdx.x * 4 + wave) * 16;
    f32x4 acc[6] = {};
    #pragma unroll 4
    for (int kt = 0; kt < 24; ++kt) {
        bf16x8 a = *(const bf16x8*)(attn + (size_t)(m0 + ln) * DMODEL + kt * 32 + quad * 8);
        #pragma unroll
        for (int nt = 0; nt < 6; ++nt) {
            bf16x8 bb = *(const bf16x8*)(WoT + (nt * 16 + ln) * DMODEL + kt * 32 + quad * 8);
            acc[nt] = __builtin_amdgcn_mfma_f32_16x16x32_bf16(a, bb, acc[nt], 0, 0, 0);
        }
    }
    int row = m0 + quad * 4;
    #pragma unroll
    for (int nt = 0; nt < 6; ++nt) {
        int col = nt * 16 + ln;
        float bb = bo[col];
        #pragma unroll
        for (int r = 0; r < 4; ++r)
            proj[(row + r) * 96 + col] = acc[nt][r] + bb;
    }
}

// ---------------------------------------------------------------------------
// 6) Broadcast residual: out[i,j,k,l] = proj[j,k,l] + xn[i,j,l]
//    block per (i,j): 256 threads x 9 float4 iters, coalesced stores.
// ---------------------------------------------------------------------------
__global__ __launch_bounds__(256) void bcast_kernel(
        const float* __restrict__ proj, const float* __restrict__ xn,
        float* __restrict__ out) {
    int i = blockIdx.x / 96, j = blockIdx.x - i * 96;
    __shared__ float4 xrow[24];
    if (threadIdx.x < 24)
        xrow[threadIdx.x] = ((const float4*)(xn + (i * 96 + j) * 96))[threadIdx.x];
    __syncthreads();
    const float4* p4 = (const float4*)proj + j * 2304;
    float4* o4 = (float4*)out + (size_t)(i * 96 + j) * 2304;
    #pragma unroll
    for (int it = 0; it < 9; ++it) {
        int idx = threadIdx.x + it * 256;
        int kk = idx / 24;
        int l4 = idx - kk * 24;
        float4 pv = p4[idx];
        float4 xv = xrow[l4];
        float4 rr;
        rr.x = pv.x + xv.x; rr.y = pv.y + xv.y;
        rr.z = pv.z + xv.z; rr.w = pv.w + xv.w;
        o4[idx] = rr;
    }
}

// ---------------------------------------------------------------------------
extern "C" void kernel_launch(void* const* d_in, const int* in_sizes, int n_in,
                              void* d_out, int out_size, void* d_ws, size_t ws_size,
                              hipStream_t stream) {
    const float* x     = (const float*)d_in[0];
    const float* Wq    = (const float*)d_in[1];
    const float* bq    = (const float*)d_in[2];
    const float* Wk    = (const float*)d_in[3];
    const float* bk    = (const float*)d_in[4];
    const float* Wv    = (const float*)d_in[5];
    const float* bv    = (const float*)d_in[6];
    const float* Wo    = (const float*)d_in[7];
    const float* bo    = (const float*)d_in[8];
    const float* gamma = (const float*)d_in[9];
    const float* beta  = (const float*)d_in[10];
    float* out = (float*)d_out;

    // workspace layout (bytes), total ~66.1 MB
    char* ws = (char*)d_ws;
    float* xn_f = (float*)(ws + 0);                 //  3,538,944
    u16*  xn_b  = (u16*)(ws + 3538944);             //  1,769,472
    u16*  WqT   = (u16*)(ws + 5308416);             //    147,456
    u16*  WkT   = (u16*)(ws + 5455872);
    u16*  WvT   = (u16*)(ws + 5603328);
    u16*  WoT   = (u16*)(ws + 5750784);
    u16*  qb    = (u16*)(ws + 5898240);             // 14,155,776
    u16*  kb    = (u16*)(ws + 20054016);
    u16*  vb    = (u16*)(ws + 34209792);
    u16*  ab    = (u16*)(ws + 48365568);
    float* proj = (float*)(ws + 62521344);          //  3,538,944 -> 66,060,288

    gn_kernel<<<dim3(BATCH * GRP), dim3(128), 0, stream>>>(x, gamma, beta, xn_f, xn_b);
    wconv_kernel<<<dim3(288, 4), dim3(256), 0, stream>>>(Wq, Wk, Wv, Wo, WqT, WkT, WvT, WoT);
    qkv_kernel<<<dim3(72, 6, 3), dim3(256), 0, stream>>>(xn_b, WqT, WkT, WvT,
                                                         bq, bk, bv, qb, kb, vb);
    attn_kernel<<<dim3(BATCH * NHEAD), dim3(384), 0, stream>>>(qb, kb, vb, ab);
    oproj_kernel<<<dim3(144), dim3(256), 0, stream>>>(ab, WoT, bo, proj);
    bcast_kernel<<<dim3(96 * 96), dim3(256), 0, stream>>>(proj, xn_f, out);
}

// Round 2
// 428.809 us; speedup vs baseline: 1.0111x; 1.0111x over previous
//
#include <hip/hip_runtime.h>
#include <hip/hip_bf16.h>

// Problem constants
#define BATCH 96
#define CH    96
#define SEQ   96
#define NHEAD 8
#define DK    96
#define DMODEL 768   // NHEAD*DK
#define GRP   8
#define EPSV  1e-5f

typedef __bf16 bf16x8 __attribute__((ext_vector_type(8)));
typedef float  f32x4  __attribute__((ext_vector_type(4)));
typedef unsigned short u16;

#define MFMA16(a, b, c) __builtin_amdgcn_mfma_f32_16x16x32_bf16((a), (b), (c), 0, 0, 0)

__device__ __forceinline__ u16 f2bf(float f) {
    union { float f; unsigned int u; } c; c.f = f;
    unsigned int u = c.u + 0x7fffu + ((c.u >> 16) & 1u);   // RNE
    return (u16)(u >> 16);
}

// ---------------------------------------------------------------------------
// 1) GroupNorm: x (96,96,1,96) -> xn fp32 + xn bf16.  One block per (b,g).
//    group g = channels [12g,12g+12), 1152 elems. 128 threads x 9 elems.
// ---------------------------------------------------------------------------
__global__ __launch_bounds__(128) void gn_kernel(
        const float* __restrict__ x, const float* __restrict__ gamma,
        const float* __restrict__ beta, float* __restrict__ xn,
        u16* __restrict__ xn_bf) {
    int bg = blockIdx.x;
    int b = bg >> 3, g = bg & 7;
    const float* xp = x + b * 9216 + g * 1152;
    float vals[9];
    float s = 0.f, ss = 0.f;
    #pragma unroll
    for (int r = 0; r < 9; ++r) {
        float v = xp[threadIdx.x + 128 * r];
        vals[r] = v; s += v; ss += v * v;
    }
    #pragma unroll
    for (int off = 32; off > 0; off >>= 1) {
        s  += __shfl_down(s, off);
        ss += __shfl_down(ss, off);
    }
    __shared__ float red[4];
    if ((threadIdx.x & 63) == 0) {
        red[(threadIdx.x >> 6) * 2]     = s;
        red[(threadIdx.x >> 6) * 2 + 1] = ss;
    }
    __syncthreads();
    s = red[0] + red[2]; ss = red[1] + red[3];
    float mu   = s * (1.0f / 1152.0f);
    float var  = ss * (1.0f / 1152.0f) - mu * mu;
    float rsig = rsqrtf(var + EPSV);
    #pragma unroll
    for (int r = 0; r < 9; ++r) {
        int e = threadIdx.x + 128 * r;
        int c = g * 12 + e / 96;
        float v = (vals[r] - mu) * rsig * gamma[c] + beta[c];
        int idx = b * 9216 + g * 1152 + e;
        xn[idx]    = v;
        xn_bf[idx] = f2bf(v);
    }
}

// ---------------------------------------------------------------------------
// 2) Weight transpose + bf16 cast.
//    seg 0..2: W (96,768) -> WT (768,96);  seg 3: Wo (768,96) -> WoT (96,768)
// ---------------------------------------------------------------------------
__global__ __launch_bounds__(256) void wconv_kernel(
        const float* __restrict__ Wq, const float* __restrict__ Wk,
        const float* __restrict__ Wv, const float* __restrict__ Wo,
        u16* __restrict__ WqT, u16* __restrict__ WkT,
        u16* __restrict__ WvT, u16* __restrict__ WoT) {
    int seg = blockIdx.y;
    const float* src = seg == 0 ? Wq : seg == 1 ? Wk : seg == 2 ? Wv : Wo;
    u16* dst = seg == 0 ? WqT : seg == 1 ? WkT : seg == 2 ? WvT : WoT;
    int idx = blockIdx.x * 256 + threadIdx.x;          // 73728 total
    if (idx < 73728) {
        if (seg < 3) {
            int n = idx / 96, k2 = idx - n * 96;        // dst[n][k2]
            dst[idx] = f2bf(src[k2 * 768 + n]);
        } else {
            int n = idx / 768, k2 = idx - n * 768;      // dst[n][k2]
            dst[idx] = f2bf(src[k2 * 96 + n]);
        }
    }
}

// ---------------------------------------------------------------------------
// 3) Fused QKV + attention per (b,h).  grid 768, block 384 (6 waves).
//    wave w: q,k rows [16w,16w+16), v^T d-rows [16w,16w+16) via swapped
//    MFMA operands (V^T = Wv^T @ t^T) -> no transpose scatter.
//    Then QK^T -> causal softmax (registers) -> P@V; P reuses kb LDS.
// ---------------------------------------------------------------------------
__global__ __launch_bounds__(384) void fattn_kernel(
        const u16* __restrict__ xn_bf,
        const u16* __restrict__ WqT, const u16* __restrict__ WkT,
        const u16* __restrict__ WvT,
        const float* __restrict__ bq, const float* __restrict__ bk,
        const float* __restrict__ bv,
        u16* __restrict__ attn_out) {
    int b = blockIdx.x >> 3, h = blockIdx.x & 7;
    __shared__ __align__(16) u16 qb[96][104];
    __shared__ __align__(16) u16 kb[96][104];   // reused for P after QK^T
    __shared__ __align__(16) u16 vt[96][104];   // vt[d][s]

    int wave = threadIdx.x >> 6, lane = threadIdx.x & 63;
    int ln = lane & 15, quad = lane >> 4;
    int m0 = wave * 16;
    const u16* xb = xn_bf + b * 9216;
    const int hq = h * 96;

    // ---- QKV projection ----
    bf16x8 a[3], av[3];
    #pragma unroll
    for (int kt = 0; kt < 3; ++kt) {
        a[kt]  = *(const bf16x8*)(xb + (m0 + ln) * 96 + kt * 32 + quad * 8);
        av[kt] = *(const bf16x8*)(WvT + (hq + m0 + ln) * 96 + kt * 32 + quad * 8);
    }
    f32x4 aq[6] = {}, ak[6] = {}, avv[6] = {};
    #pragma unroll
    for (int kt = 0; kt < 3; ++kt) {
        #pragma unroll
        for (int nt = 0; nt < 6; ++nt) {
            bf16x8 bqf = *(const bf16x8*)(WqT + (hq + nt * 16 + ln) * 96 + kt * 32 + quad * 8);
            aq[nt] = MFMA16(a[kt], bqf, aq[nt]);
            bf16x8 bkf = *(const bf16x8*)(WkT + (hq + nt * 16 + ln) * 96 + kt * 32 + quad * 8);
            ak[nt] = MFMA16(a[kt], bkf, ak[nt]);
            bf16x8 bvf = *(const bf16x8*)(xb + (nt * 16 + ln) * 96 + kt * 32 + quad * 8);
            avv[nt] = MFMA16(av[kt], bvf, avv[nt]);
        }
    }
    float bvr[4];
    #pragma unroll
    for (int r = 0; r < 4; ++r) bvr[r] = bv[hq + m0 + quad * 4 + r];
    #pragma unroll
    for (int nt = 0; nt < 6; ++nt) {
        int col = nt * 16 + ln;
        float bqc = bq[hq + col], bkc = bk[hq + col];
        #pragma unroll
        for (int r = 0; r < 4; ++r) {
            int row = m0 + quad * 4 + r;
            qb[row][col] = f2bf(aq[nt][r] + bqc);
            kb[row][col] = f2bf(ak[nt][r] + bkc);
            vt[row][col] = f2bf(avv[nt][r] + bvr[r]);   // row=d, col=s
        }
    }
    __syncthreads();

    // ---- scores = QK^T ----
    f32x4 accs[6] = {};
    #pragma unroll
    for (int kt = 0; kt < 3; ++kt) {
        bf16x8 aa = *(const bf16x8*)(&qb[m0 + ln][kt * 32 + quad * 8]);
        #pragma unroll
        for (int nt = 0; nt < 6; ++nt) {
            bf16x8 bb = *(const bf16x8*)(&kb[nt * 16 + ln][kt * 32 + quad * 8]);
            accs[nt] = MFMA16(aa, bb, accs[nt]);
        }
    }

    // ---- causal softmax in registers; C layout row=quad*4+r, col=nt*16+ln
    const float scale = 0.10206207261596577f;   // 1/sqrt(96)
    float pout[4][6];
    #pragma unroll
    for (int r = 0; r < 4; ++r) {
        int row = m0 + quad * 4 + r;
        float vals[6], m = -1e30f;
        #pragma unroll
        for (int nt = 0; nt < 6; ++nt) {
            int col = nt * 16 + ln;
            float sv = accs[nt][r] * scale;
            vals[nt] = (col <= row) ? sv : -1e30f;
            m = fmaxf(m, vals[nt]);
        }
        #pragma unroll
        for (int off = 1; off < 16; off <<= 1) m = fmaxf(m, __shfl_xor(m, off));
        float sum = 0.f;
        #pragma unroll
        for (int nt = 0; nt < 6; ++nt) {
            float p = (vals[nt] > -1e29f) ? __expf(vals[nt] - m) : 0.f;
            pout[r][nt] = p; sum += p;
        }
        #pragma unroll
        for (int off = 1; off < 16; off <<= 1) sum += __shfl_xor(sum, off);
        float rinv = 1.0f / sum;
        #pragma unroll
        for (int nt = 0; nt < 6; ++nt) pout[r][nt] *= rinv;
    }
    __syncthreads();          // all waves done reading kb
    #pragma unroll
    for (int r = 0; r < 4; ++r)
        #pragma unroll
        for (int nt = 0; nt < 6; ++nt)
            kb[m0 + quad * 4 + r][nt * 16 + ln] = f2bf(pout[r][nt]);
    __syncthreads();          // P visible to all waves

    // ---- O = P @ V  (A = P rows, B = vt rows) ----
    f32x4 acco[6] = {};
    #pragma unroll
    for (int kt = 0; kt < 3; ++kt) {
        bf16x8 aa = *(const bf16x8*)(&kb[m0 + ln][kt * 32 + quad * 8]);
        #pragma unroll
        for (int nt = 0; nt < 6; ++nt) {
            bf16x8 bb = *(const bf16x8*)(&vt[nt * 16 + ln][kt * 32 + quad * 8]);
            acco[nt] = MFMA16(aa, bb, acco[nt]);
        }
    }
    const size_t obase = (size_t)b * 96 * DMODEL + hq;
    #pragma unroll
    for (int nt = 0; nt < 6; ++nt) {
        int d = nt * 16 + ln;
        #pragma unroll
        for (int r = 0; r < 4; ++r) {
            int row = m0 + quad * 4 + r;
            attn_out[obase + (size_t)row * DMODEL + d] = f2bf(acco[nt][r]);
        }
    }
}

// ---------------------------------------------------------------------------
// 4) Out projection, 4-way K-split: attn(9216x768)@Wo(768x96)+bo -> proj f32
//    grid 576 (16 rows each), block 256 = 4 waves (one K-quarter each),
//    LDS reduction across waves.
// ---------------------------------------------------------------------------
__global__ __launch_bounds__(256) void oproj_kernel(
        const u16* __restrict__ attn, const u16* __restrict__ WoT,
        const float* __restrict__ bo, float* __restrict__ proj) {
    int wave = threadIdx.x >> 6, lane = threadIdx.x & 63;
    int ln = lane & 15, quad = lane >> 4;
    int m0 = blockIdx.x * 16;
    int k0 = wave * 192;
    f32x4 acc[6] = {};
    #pragma unroll
    for (int kt = 0; kt < 6; ++kt) {
        bf16x8 a = *(const bf16x8*)(attn + (size_t)(m0 + ln) * DMODEL + k0 + kt * 32 + quad * 8);
        #pragma unroll
        for (int nt = 0; nt < 6; ++nt) {
            bf16x8 bb = *(const bf16x8*)(WoT + (nt * 16 + ln) * DMODEL + k0 + kt * 32 + quad * 8);
            acc[nt] = MFMA16(a, bb, acc[nt]);
        }
    }
    __shared__ float red[4][16][96];
    #pragma unroll
    for (int nt = 0; nt < 6; ++nt)
        #pragma unroll
        for (int r = 0; r < 4; ++r)
            red[wave][quad * 4 + r][nt * 16 + ln] = acc[nt][r];
    __syncthreads();
    #pragma unroll
    for (int e = 0; e < 6; ++e) {
        int idx = threadIdx.x + e * 256;        // 1536 outputs
        int row = idx / 96, col = idx - row * 96;
        float s = red[0][row][col] + red[1][row][col] +
                  red[2][row][col] + red[3][row][col] + bo[col];
        proj[(m0 + row) * 96 + col] = s;
    }
}

// ---------------------------------------------------------------------------
// 5) Broadcast residual: out[i,j,k,l] = proj[j,k,l] + xn[i,j,l]
//    block per (i,j): 256 threads x 9 float4 iters, coalesced stores.
// ---------------------------------------------------------------------------
__global__ __launch_bounds__(256) void bcast_kernel(
        const float* __restrict__ proj, const float* __restrict__ xn,
        float* __restrict__ out) {
    int i = blockIdx.x / 96, j = blockIdx.x - i * 96;
    __shared__ float4 xrow[24];
    if (threadIdx.x < 24)
        xrow[threadIdx.x] = ((const float4*)(xn + (i * 96 + j) * 96))[threadIdx.x];
    __syncthreads();
    const float4* p4 = (const float4*)proj + j * 2304;
    float4* o4 = (float4*)out + (size_t)(i * 96 + j) * 2304;
    #pragma unroll
    for (int it = 0; it < 9; ++it) {
        int idx = threadIdx.x + it * 256;
        int kk = idx / 24;
        int l4 = idx - kk * 24;
        float4 pv = p4[idx];
        float4 xv = xrow[l4];
        float4 rr;
        rr.x = pv.x + xv.x; rr.y = pv.y + xv.y;
        rr.z = pv.z + xv.z; rr.w = pv.w + xv.w;
        o4[idx] = rr;
    }
}

// ---------------------------------------------------------------------------
extern "C" void kernel_launch(void* const* d_in, const int* in_sizes, int n_in,
                              void* d_out, int out_size, void* d_ws, size_t ws_size,
                              hipStream_t stream) {
    const float* x     = (const float*)d_in[0];
    const float* Wq    = (const float*)d_in[1];
    const float* bq    = (const float*)d_in[2];
    const float* Wk    = (const float*)d_in[3];
    const float* bk    = (const float*)d_in[4];
    const float* Wv    = (const float*)d_in[5];
    const float* bv    = (const float*)d_in[6];
    const float* Wo    = (const float*)d_in[7];
    const float* bo    = (const float*)d_in[8];
    const float* gamma = (const float*)d_in[9];
    const float* beta  = (const float*)d_in[10];
    float* out = (float*)d_out;

    // workspace layout (bytes), total ~23.6 MB
    char* ws = (char*)d_ws;
    float* xn_f = (float*)(ws + 0);                 //  3,538,944
    u16*  xn_b  = (u16*)(ws + 3538944);             //  1,769,472
    u16*  WqT   = (u16*)(ws + 5308416);             //    147,456
    u16*  WkT   = (u16*)(ws + 5455872);
    u16*  WvT   = (u16*)(ws + 5603328);
    u16*  WoT   = (u16*)(ws + 5750784);
    u16*  ab    = (u16*)(ws + 5898240);             // 14,155,776
    float* proj = (float*)(ws + 20054016);          //  3,538,944 -> 23,592,960

    gn_kernel<<<dim3(BATCH * GRP), dim3(128), 0, stream>>>(x, gamma, beta, xn_f, xn_b);
    wconv_kernel<<<dim3(288, 4), dim3(256), 0, stream>>>(Wq, Wk, Wv, Wo, WqT, WkT, WvT, WoT);
    fattn_kernel<<<dim3(BATCH * NHEAD), dim3(384), 0, stream>>>(
        xn_b, WqT, WkT, WvT, bq, bk, bv, ab);
    oproj_kernel<<<dim3(576), dim3(256), 0, stream>>>(ab, WoT, bo, proj);
    bcast_kernel<<<dim3(96 * 96), dim3(256), 0, stream>>>(proj, xn_f, out);
}